// Round 4
// baseline (85.738 us; speedup 1.0000x reference)
//
#include <hip/hip_runtime.h>

#define B_   4
#define K_   6
#define BK_  (B_ * K_)
#define C_   128
#define CB_  (C_ / 4)         // 32 channel-blocks of 4
#define HF_  32
#define WF_  88
#define P_   (HF_ * WF_)      // 2816 pixels per (b,k) feature map
#define BEV  256
#define NPTS (BEV * BEV)      // 65536
#define CSPLIT 4              // channel slices (grid.z)
#define CBPT (CB_ / CSPLIT)   // 8 channel-blocks per thread

// ---------------------------------------------------------------------------
// Kernel 1: shuffle features [BK, C, P] -> [BK, C/4, P, 4] (channel-blocked).
// Each 128-B line holds one 4-channel block of 8 consecutive pixels.
// ---------------------------------------------------------------------------
__global__ __launch_bounds__(256) void shuffle_feat(
    const float* __restrict__ in, float* __restrict__ outT)
{
    __shared__ float lds[64][C_ + 1];
    const int bk  = blockIdx.y;
    const int p0  = blockIdx.x * 64;
    const int tid = threadIdx.x;

    const int pl = tid & 63;        // pixel within tile
    const int cq = tid >> 6;        // 0..3 channel sub-lane (read phase)
    const float* src = in + (size_t)bk * C_ * P_;
#pragma unroll
    for (int c0 = 0; c0 < C_; c0 += 4) {
        const int c = c0 + cq;
        lds[pl][c] = src[(size_t)c * P_ + p0 + pl];
    }
    __syncthreads();

    // write phase: float4 = 4 channels of one pixel, lanes over pixels
    float* dst = outT + (size_t)bk * CB_ * P_ * 4;
    const int cbq = tid >> 6;       // 0..3 cb sub-lane
#pragma unroll
    for (int cb0 = 0; cb0 < CB_; cb0 += 4) {
        const int cb = cb0 + cbq;
        float4 v;
        v.x = lds[pl][cb * 4 + 0];
        v.y = lds[pl][cb * 4 + 1];
        v.z = lds[pl][cb * 4 + 2];
        v.w = lds[pl][cb * 4 + 3];
        *(float4*)(dst + ((size_t)cb * P_ + p0 + pl) * 4) = v;
    }
}

// ---------------------------------------------------------------------------
// Kernel 2: per-BEV-point projection + bilinear sampling over 6 cameras.
// Grid: (BEV rows, B, CSPLIT); block 256 (ix lane). Channel-blocked gathers.
// j-loop unrolled x2 so the compiler overlaps next iteration's gathers with
// current iteration's FMAs (MLP; we are latency-bound, not BW-bound).
// ---------------------------------------------------------------------------
template <bool TRANS>
__global__ __launch_bounds__(256) void bev_project(
    const float* __restrict__ feat,
    const float* __restrict__ intr,   // [B,K,3,3]
    const float* __restrict__ extr,   // [B,K,4,4]
    float* __restrict__ out)          // [B,C,BEV,BEV]
{
    const int ix = threadIdx.x;
    const int iy = blockIdx.x;
    const int b  = blockIdx.y;
    const int cs = blockIdx.z;

    const float STEP = 102.4f / 255.0f;
    const float gx = -51.2f + ix * STEP;
    const float gy = -51.2f + iy * STEP;

    int   off[K_], dX[K_], dY[K_];
    float w00[K_], w01[K_], w10[K_], w11[K_];
    bool  val[K_];
    float cnt = 0.0f;

#pragma unroll
    for (int k = 0; k < K_; ++k) {
        const float* E = extr + (size_t)(b * K_ + k) * 16;
        const float* I = intr + (size_t)(b * K_ + k) * 9;
        // world z = 0, w = 1
        const float c0 = E[0] * gx + E[1] * gy + E[3];
        const float c1 = E[4] * gx + E[5] * gy + E[7];
        const float c2 = E[8] * gx + E[9] * gy + E[11];
        const float uu = I[0] * c0 + I[1] * c1 + I[2] * c2;
        const float vv = I[3] * c0 + I[4] * c1 + I[5] * c2;
        const float ww = I[6] * c0 + I[7] * c1 + I[8] * c2;
        const float depth = fmaxf(ww, 1e-5f);
        const float u = uu / depth * 0.125f;   // sx = 88/704
        const float v = vv / depth * 0.125f;   // sy = 32/256
        const bool valid = (ww > 1e-3f) && (u >= 0.0f) && (u <= (float)(WF_ - 1))
                                        && (v >= 0.0f) && (v <= (float)(HF_ - 1));
        const float uc = fminf(fmaxf(u, 0.0f), (float)(WF_ - 1));
        const float vc = fminf(fmaxf(v, 0.0f), (float)(HF_ - 1));
        const float x0f = floorf(uc), y0f = floorf(vc);
        const int x0 = (int)x0f, y0 = (int)y0f;
        const int x1 = min(x0 + 1, WF_ - 1), y1 = min(y0 + 1, HF_ - 1);
        const float wx = uc - x0f, wy = vc - y0f;

        val[k] = valid;
        cnt += valid ? 1.0f : 0.0f;
        w00[k] = (1.0f - wx) * (1.0f - wy);
        w01[k] = wx * (1.0f - wy);
        w10[k] = (1.0f - wx) * wy;
        w11[k] = wx * wy;

        const int pix = y0 * WF_ + x0;
        if (TRANS) {
            // base addr (floats) of channel-block 0, this pixel
            off[k] = ((b * K_ + k) * CB_ * P_ + pix) * 4;
            dX[k]  = (x1 - x0) * 4;          // next pixel: 16 B (same line)
            dY[k]  = (y1 - y0) * (WF_ * 4);  // next row
        } else {
            off[k] = (b * K_ + k) * (C_ * P_) + pix;
            dX[k]  = (x1 - x0);
            dY[k]  = (y1 - y0) * WF_;
        }
    }

    const float inv = 1.0f / fmaxf(cnt, 1.0f);
#pragma unroll
    for (int k = 0; k < K_; ++k) {       // fold 1/count into the weights
        w00[k] *= inv; w01[k] *= inv; w10[k] *= inv; w11[k] *= inv;
    }

    float* outp = out + (size_t)b * C_ * NPTS + (size_t)(cs * CBPT * 4) * NPTS
                      + (size_t)iy * BEV + ix;

    if (TRANS) {
        const float* bp[K_];
#pragma unroll
        for (int k = 0; k < K_; ++k)
            bp[k] = feat + off[k] + (size_t)(cs * CBPT) * (P_ * 4);

#pragma unroll 2
        for (int j = 0; j < CBPT; ++j) {
            float ax = 0.0f, ay = 0.0f, az = 0.0f, aw = 0.0f;
#pragma unroll
            for (int k = 0; k < K_; ++k) {
                if (!val[k]) continue;
                const float* pb = bp[k] + j * (P_ * 4);
                const float4 f00 = *(const float4*)(pb);
                const float4 f01 = *(const float4*)(pb + dX[k]);
                const float4 f10 = *(const float4*)(pb + dY[k]);
                const float4 f11 = *(const float4*)(pb + dX[k] + dY[k]);
                ax += w00[k] * f00.x + w01[k] * f01.x + w10[k] * f10.x + w11[k] * f11.x;
                ay += w00[k] * f00.y + w01[k] * f01.y + w10[k] * f10.y + w11[k] * f11.y;
                az += w00[k] * f00.z + w01[k] * f01.z + w10[k] * f10.z + w11[k] * f11.z;
                aw += w00[k] * f00.w + w01[k] * f01.w + w10[k] * f10.w + w11[k] * f11.w;
            }
            __builtin_nontemporal_store(ax, &outp[(size_t)(j * 4 + 0) * NPTS]);
            __builtin_nontemporal_store(ay, &outp[(size_t)(j * 4 + 1) * NPTS]);
            __builtin_nontemporal_store(az, &outp[(size_t)(j * 4 + 2) * NPTS]);
            __builtin_nontemporal_store(aw, &outp[(size_t)(j * 4 + 3) * NPTS]);
        }
    } else {
#pragma unroll 1
        for (int c = 0; c < CBPT * 4; ++c) {
            float a = 0.0f;
#pragma unroll
            for (int k = 0; k < K_; ++k) {
                if (!val[k]) continue;
                const float* pb = feat + off[k] + (size_t)(cs * CBPT * 4 + c) * P_;
                a += w00[k] * pb[0] + w01[k] * pb[dX[k]]
                   + w10[k] * pb[dY[k]] + w11[k] * pb[dX[k] + dY[k]];
            }
            __builtin_nontemporal_store(a, &outp[(size_t)c * NPTS]);
        }
    }
}

extern "C" void kernel_launch(void* const* d_in, const int* in_sizes, int n_in,
                              void* d_out, int out_size, void* d_ws, size_t ws_size,
                              hipStream_t stream) {
    const float* features   = (const float*)d_in[0];
    const float* intrinsics = (const float*)d_in[1];
    const float* extrinsics = (const float*)d_in[2];
    float* out = (float*)d_out;

    const size_t need = sizeof(float) * (size_t)BK_ * C_ * P_;  // ~33 MB
    if (ws_size >= need) {
        float* featT = (float*)d_ws;
        shuffle_feat<<<dim3(P_ / 64, BK_), 256, 0, stream>>>(features, featT);
        bev_project<true><<<dim3(BEV, B_, CSPLIT), 256, 0, stream>>>(
            featT, intrinsics, extrinsics, out);
    } else {
        bev_project<false><<<dim3(BEV, B_, CSPLIT), 256, 0, stream>>>(
            features, intrinsics, extrinsics, out);
    }
}

// Round 6
// 70.679 us; speedup vs baseline: 1.2131x; 1.2131x over previous
//
#include <hip/hip_runtime.h>

#define B_   4
#define K_   6
#define BK_  (B_ * K_)
#define C_   128
#define CB_  (C_ / 4)         // 32 channel-blocks of 4
#define HF_  32
#define WF_  88
#define P_   (HF_ * WF_)      // 2816 pixels per (b,k) feature map
#define BEV  256
#define NPTS (BEV * BEV)      // 65536
#define CSPLIT 4              // channel slices (grid.z)
#define CBPT (CB_ / CSPLIT)   // 8 channel-blocks per thread

__device__ __forceinline__ unsigned short f32_to_bf16_rne(float f) {
    union { float f; unsigned int u; } c; c.f = f;
    unsigned int u = c.u;
    u += 0x7fffu + ((u >> 16) & 1u);   // round to nearest even
    return (unsigned short)(u >> 16);
}
__device__ __forceinline__ float bf_lo(unsigned int w) {
    union { unsigned int u; float f; } c; c.u = w << 16; return c.f;
}
__device__ __forceinline__ float bf_hi(unsigned int w) {
    union { unsigned int u; float f; } c; c.u = w & 0xffff0000u; return c.f;
}

// ---------------------------------------------------------------------------
// Kernel 1: shuffle features [BK, C, P] (f32) -> [BK, C/4, P, 4] packed bf16.
// 8 B per (pixel, 4-channel block); one 128-B line = 16 consecutive pixels.
// ---------------------------------------------------------------------------
__global__ __launch_bounds__(256) void shuffle_feat_bf16(
    const float* __restrict__ in, unsigned long long* __restrict__ outT)
{
    __shared__ float lds[64][C_ + 1];
    const int bk  = blockIdx.y;
    const int p0  = blockIdx.x * 64;
    const int tid = threadIdx.x;

    const int pl = tid & 63;        // pixel within tile
    const int cq = tid >> 6;        // 0..3 channel sub-lane (read phase)
    const float* src = in + (size_t)bk * C_ * P_;
#pragma unroll
    for (int c0 = 0; c0 < C_; c0 += 4) {
        const int c = c0 + cq;
        lds[pl][c] = src[(size_t)c * P_ + p0 + pl];
    }
    __syncthreads();

    // write phase: pack 4 channels of one pixel into 8 B; lanes over pixels
    unsigned long long* dst = outT + (size_t)bk * CB_ * P_;
    const int cbq = tid >> 6;       // 0..3 cb sub-lane
#pragma unroll
    for (int cb0 = 0; cb0 < CB_; cb0 += 4) {
        const int cb = cb0 + cbq;
        unsigned short h0 = f32_to_bf16_rne(lds[pl][cb * 4 + 0]);
        unsigned short h1 = f32_to_bf16_rne(lds[pl][cb * 4 + 1]);
        unsigned short h2 = f32_to_bf16_rne(lds[pl][cb * 4 + 2]);
        unsigned short h3 = f32_to_bf16_rne(lds[pl][cb * 4 + 3]);
        unsigned int w0 = (unsigned int)h0 | ((unsigned int)h1 << 16);
        unsigned int w1 = (unsigned int)h2 | ((unsigned int)h3 << 16);
        dst[(size_t)cb * P_ + p0 + pl] =
            (unsigned long long)w0 | ((unsigned long long)w1 << 32);
    }
}

// ---------------------------------------------------------------------------
// Kernel 2: per-BEV-point projection + bilinear sampling over 6 cameras.
// Grid: (BEV rows, B, CSPLIT); block 256 (ix lane). bf16 channel-blocked
// gathers (8 B per corner), f32 geometry + accumulation.
// ---------------------------------------------------------------------------
template <bool TRANS>
__global__ __launch_bounds__(256) void bev_project(
    const void* __restrict__ featv,
    const float* __restrict__ intr,   // [B,K,3,3]
    const float* __restrict__ extr,   // [B,K,4,4]
    float* __restrict__ out)          // [B,C,BEV,BEV]
{
    const int ix = threadIdx.x;
    const int iy = blockIdx.x;
    const int b  = blockIdx.y;
    const int cs = blockIdx.z;

    const float STEP = 102.4f / 255.0f;
    const float gx = -51.2f + ix * STEP;
    const float gy = -51.2f + iy * STEP;

    int   off[K_], dX[K_], dY[K_];
    float w00[K_], w01[K_], w10[K_], w11[K_];
    bool  val[K_];
    float cnt = 0.0f;

#pragma unroll
    for (int k = 0; k < K_; ++k) {
        const float* E = extr + (size_t)(b * K_ + k) * 16;
        const float* I = intr + (size_t)(b * K_ + k) * 9;
        // world z = 0, w = 1
        const float c0 = E[0] * gx + E[1] * gy + E[3];
        const float c1 = E[4] * gx + E[5] * gy + E[7];
        const float c2 = E[8] * gx + E[9] * gy + E[11];
        const float uu = I[0] * c0 + I[1] * c1 + I[2] * c2;
        const float vv = I[3] * c0 + I[4] * c1 + I[5] * c2;
        const float ww = I[6] * c0 + I[7] * c1 + I[8] * c2;
        const float depth = fmaxf(ww, 1e-5f);
        const float u = uu / depth * 0.125f;   // sx = 88/704
        const float v = vv / depth * 0.125f;   // sy = 32/256
        const bool valid = (ww > 1e-3f) && (u >= 0.0f) && (u <= (float)(WF_ - 1))
                                        && (v >= 0.0f) && (v <= (float)(HF_ - 1));
        const float uc = fminf(fmaxf(u, 0.0f), (float)(WF_ - 1));
        const float vc = fminf(fmaxf(v, 0.0f), (float)(HF_ - 1));
        const float x0f = floorf(uc), y0f = floorf(vc);
        const int x0 = (int)x0f, y0 = (int)y0f;
        const int x1 = min(x0 + 1, WF_ - 1), y1 = min(y0 + 1, HF_ - 1);
        const float wx = uc - x0f, wy = vc - y0f;

        val[k] = valid;
        cnt += valid ? 1.0f : 0.0f;
        w00[k] = (1.0f - wx) * (1.0f - wy);
        w01[k] = wx * (1.0f - wy);
        w10[k] = (1.0f - wx) * wy;
        w11[k] = wx * wy;

        const int pix = y0 * WF_ + x0;
        if (TRANS) {
            off[k] = ((b * K_ + k) * CB_ * P_ + pix) * 8;  // byte offset
            dX[k]  = (x1 - x0) * 8;                        // bytes
            dY[k]  = (y1 - y0) * (WF_ * 8);                // bytes
        } else {
            off[k] = (b * K_ + k) * (C_ * P_) + pix;
            dX[k]  = (x1 - x0);
            dY[k]  = (y1 - y0) * WF_;
        }
    }

    const float inv = 1.0f / fmaxf(cnt, 1.0f);
#pragma unroll
    for (int k = 0; k < K_; ++k) {       // fold 1/count into the weights
        w00[k] *= inv; w01[k] *= inv; w10[k] *= inv; w11[k] *= inv;
    }

    float* outp = out + (size_t)b * C_ * NPTS + (size_t)(cs * CBPT * 4) * NPTS
                      + (size_t)iy * BEV + ix;

    if (TRANS) {
        const char* bp[K_];
#pragma unroll
        for (int k = 0; k < K_; ++k)
            bp[k] = (const char*)featv + off[k] + (size_t)(cs * CBPT) * (P_ * 8);

#pragma unroll 1
        for (int j = 0; j < CBPT; ++j) {
            float a0 = 0.0f, a1 = 0.0f, a2 = 0.0f, a3 = 0.0f;
#pragma unroll
            for (int k = 0; k < K_; ++k) {
                if (!val[k]) continue;
                const char* pb = bp[k] + j * (P_ * 8);
                const uint2 q00 = *(const uint2*)(pb);
                const uint2 q01 = *(const uint2*)(pb + dX[k]);
                const uint2 q10 = *(const uint2*)(pb + dY[k]);
                const uint2 q11 = *(const uint2*)(pb + dX[k] + dY[k]);
                a0 += w00[k] * bf_lo(q00.x) + w01[k] * bf_lo(q01.x)
                    + w10[k] * bf_lo(q10.x) + w11[k] * bf_lo(q11.x);
                a1 += w00[k] * bf_hi(q00.x) + w01[k] * bf_hi(q01.x)
                    + w10[k] * bf_hi(q10.x) + w11[k] * bf_hi(q11.x);
                a2 += w00[k] * bf_lo(q00.y) + w01[k] * bf_lo(q01.y)
                    + w10[k] * bf_lo(q10.y) + w11[k] * bf_lo(q11.y);
                a3 += w00[k] * bf_hi(q00.y) + w01[k] * bf_hi(q01.y)
                    + w10[k] * bf_hi(q10.y) + w11[k] * bf_hi(q11.y);
            }
            __builtin_nontemporal_store(a0, &outp[(size_t)(j * 4 + 0) * NPTS]);
            __builtin_nontemporal_store(a1, &outp[(size_t)(j * 4 + 1) * NPTS]);
            __builtin_nontemporal_store(a2, &outp[(size_t)(j * 4 + 2) * NPTS]);
            __builtin_nontemporal_store(a3, &outp[(size_t)(j * 4 + 3) * NPTS]);
        }
    } else {
        const float* feat = (const float*)featv;
#pragma unroll 1
        for (int c = 0; c < CBPT * 4; ++c) {
            float a = 0.0f;
#pragma unroll
            for (int k = 0; k < K_; ++k) {
                if (!val[k]) continue;
                const float* pb = feat + off[k] + (size_t)(cs * CBPT * 4 + c) * P_;
                a += w00[k] * pb[0] + w01[k] * pb[dX[k]]
                   + w10[k] * pb[dY[k]] + w11[k] * pb[dX[k] + dY[k]];
            }
            __builtin_nontemporal_store(a, &outp[(size_t)c * NPTS]);
        }
    }
}

extern "C" void kernel_launch(void* const* d_in, const int* in_sizes, int n_in,
                              void* d_out, int out_size, void* d_ws, size_t ws_size,
                              hipStream_t stream) {
    const float* features   = (const float*)d_in[0];
    const float* intrinsics = (const float*)d_in[1];
    const float* extrinsics = (const float*)d_in[2];
    float* out = (float*)d_out;

    const size_t need = sizeof(unsigned long long) * (size_t)BK_ * CB_ * P_;  // ~17 MB
    if (ws_size >= need) {
        unsigned long long* featT = (unsigned long long*)d_ws;
        shuffle_feat_bf16<<<dim3(P_ / 64, BK_), 256, 0, stream>>>(features, featT);
        bev_project<true><<<dim3(BEV, B_, CSPLIT), 256, 0, stream>>>(
            (const void*)featT, intrinsics, extrinsics, out);
    } else {
        bev_project<false><<<dim3(BEV, B_, CSPLIT), 256, 0, stream>>>(
            (const void*)features, intrinsics, extrinsics, out);
    }
}

// Round 7
// 62.007 us; speedup vs baseline: 1.3827x; 1.1399x over previous
//
#include <hip/hip_runtime.h>

#define B_   4
#define K_   6
#define BK_  (B_ * K_)
#define C_   128
#define C8_  (C_ / 8)         // 16 channel-blocks of 8
#define HF_  32
#define WF_  88
#define P_   (HF_ * WF_)      // 2816 pixels per (b,k) feature map
#define BEV  256
#define NPTS (BEV * BEV)      // 65536
#define CSPLIT 4              // channel slices (grid.z)
#define JPT  (C8_ / CSPLIT)   // 4 channel-blocks (of 8) per thread

__device__ __forceinline__ unsigned short f32_to_bf16_rne(float f) {
    union { float f; unsigned int u; } c; c.f = f;
    unsigned int u = c.u;
    u += 0x7fffu + ((u >> 16) & 1u);   // round to nearest even
    return (unsigned short)(u >> 16);
}
__device__ __forceinline__ float bf_lo(unsigned int w) {
    union { unsigned int u; float f; } c; c.u = w << 16; return c.f;
}
__device__ __forceinline__ float bf_hi(unsigned int w) {
    union { unsigned int u; float f; } c; c.u = w & 0xffff0000u; return c.f;
}

// ---------------------------------------------------------------------------
// Kernel 1: shuffle features [BK, C, P] (f32) -> [BK, C/8, P, 8] packed bf16.
// 16 B per (pixel, 8-channel block): one aligned uint4 gather = 8 channels.
// ---------------------------------------------------------------------------
__global__ __launch_bounds__(256) void shuffle_feat_bf16(
    const float* __restrict__ in, uint4* __restrict__ outT)
{
    __shared__ float lds[64][C_ + 1];
    const int bk  = blockIdx.y;
    const int p0  = blockIdx.x * 64;
    const int tid = threadIdx.x;

    const int pl = tid & 63;        // pixel within tile
    const int cq = tid >> 6;        // 0..3 channel sub-lane (read phase)
    const float* src = in + (size_t)bk * C_ * P_;
#pragma unroll
    for (int c0 = 0; c0 < C_; c0 += 4) {
        const int c = c0 + cq;
        lds[pl][c] = src[(size_t)c * P_ + p0 + pl];
    }
    __syncthreads();

    // write phase: pack 8 channels of one pixel into 16 B; lanes over pixels
    uint4* dst = outT + (size_t)bk * C8_ * P_;
    const int cbq = tid >> 6;       // 0..3 cb sub-lane
#pragma unroll
    for (int cb0 = 0; cb0 < C8_; cb0 += 4) {
        const int cb = cb0 + cbq;
        const float* row = &lds[pl][cb * 8];
        uint4 q;
        q.x = (unsigned int)f32_to_bf16_rne(row[0]) | ((unsigned int)f32_to_bf16_rne(row[1]) << 16);
        q.y = (unsigned int)f32_to_bf16_rne(row[2]) | ((unsigned int)f32_to_bf16_rne(row[3]) << 16);
        q.z = (unsigned int)f32_to_bf16_rne(row[4]) | ((unsigned int)f32_to_bf16_rne(row[5]) << 16);
        q.w = (unsigned int)f32_to_bf16_rne(row[6]) | ((unsigned int)f32_to_bf16_rne(row[7]) << 16);
        dst[(size_t)cb * P_ + p0 + pl] = q;
    }
}

// ---------------------------------------------------------------------------
// Kernel 2: per-BEV-point projection + bilinear sampling over 6 cameras.
// Grid: (BEV rows, B, CSPLIT); block 256 (ix lane). 8-channel bf16 blocks:
// 96 gathers/thread (vs 192) — attacks the TA address-throughput floor.
// ---------------------------------------------------------------------------
template <bool TRANS>
__global__ __launch_bounds__(256) void bev_project(
    const void* __restrict__ featv,
    const float* __restrict__ intr,   // [B,K,3,3]
    const float* __restrict__ extr,   // [B,K,4,4]
    float* __restrict__ out)          // [B,C,BEV,BEV]
{
    const int ix = threadIdx.x;
    const int iy = blockIdx.x;
    const int b  = blockIdx.y;
    const int cs = blockIdx.z;

    const float STEP = 102.4f / 255.0f;
    const float gx = -51.2f + ix * STEP;
    const float gy = -51.2f + iy * STEP;

    int   off[K_], dX[K_], dY[K_];
    float w00[K_], w01[K_], w10[K_], w11[K_];
    bool  val[K_];
    float cnt = 0.0f;

#pragma unroll
    for (int k = 0; k < K_; ++k) {
        const float* E = extr + (size_t)(b * K_ + k) * 16;
        const float* I = intr + (size_t)(b * K_ + k) * 9;
        // world z = 0, w = 1
        const float c0 = E[0] * gx + E[1] * gy + E[3];
        const float c1 = E[4] * gx + E[5] * gy + E[7];
        const float c2 = E[8] * gx + E[9] * gy + E[11];
        const float uu = I[0] * c0 + I[1] * c1 + I[2] * c2;
        const float vv = I[3] * c0 + I[4] * c1 + I[5] * c2;
        const float ww = I[6] * c0 + I[7] * c1 + I[8] * c2;
        const float depth = fmaxf(ww, 1e-5f);
        const float u = uu / depth * 0.125f;   // sx = 88/704
        const float v = vv / depth * 0.125f;   // sy = 32/256
        const bool valid = (ww > 1e-3f) && (u >= 0.0f) && (u <= (float)(WF_ - 1))
                                        && (v >= 0.0f) && (v <= (float)(HF_ - 1));
        const float uc = fminf(fmaxf(u, 0.0f), (float)(WF_ - 1));
        const float vc = fminf(fmaxf(v, 0.0f), (float)(HF_ - 1));
        const float x0f = floorf(uc), y0f = floorf(vc);
        const int x0 = (int)x0f, y0 = (int)y0f;
        const int x1 = min(x0 + 1, WF_ - 1), y1 = min(y0 + 1, HF_ - 1);
        const float wx = uc - x0f, wy = vc - y0f;

        val[k] = valid;
        cnt += valid ? 1.0f : 0.0f;
        w00[k] = (1.0f - wx) * (1.0f - wy);
        w01[k] = wx * (1.0f - wy);
        w10[k] = (1.0f - wx) * wy;
        w11[k] = wx * wy;

        const int pix = y0 * WF_ + x0;
        if (TRANS) {
            off[k] = ((b * K_ + k) * C8_ * P_ + pix) * 16;  // byte offset
            dX[k]  = (x1 - x0) * 16;                        // bytes
            dY[k]  = (y1 - y0) * (WF_ * 16);                // bytes
        } else {
            off[k] = (b * K_ + k) * (C_ * P_) + pix;
            dX[k]  = (x1 - x0);
            dY[k]  = (y1 - y0) * WF_;
        }
    }

    const float inv = 1.0f / fmaxf(cnt, 1.0f);
#pragma unroll
    for (int k = 0; k < K_; ++k) {       // fold 1/count into the weights
        w00[k] *= inv; w01[k] *= inv; w10[k] *= inv; w11[k] *= inv;
    }

    float* outp = out + (size_t)b * C_ * NPTS + (size_t)(cs * JPT * 8) * NPTS
                      + (size_t)iy * BEV + ix;

    if (TRANS) {
        const char* bp[K_];
#pragma unroll
        for (int k = 0; k < K_; ++k)
            bp[k] = (const char*)featv + off[k] + (size_t)(cs * JPT) * (P_ * 16);

#pragma unroll 1
        for (int j = 0; j < JPT; ++j) {
            float a0 = 0.0f, a1 = 0.0f, a2 = 0.0f, a3 = 0.0f;
            float a4 = 0.0f, a5 = 0.0f, a6 = 0.0f, a7 = 0.0f;
#pragma unroll
            for (int k = 0; k < K_; ++k) {
                if (!val[k]) continue;
                const char* pb = bp[k] + j * (P_ * 16);
                const uint4 q00 = *(const uint4*)(pb);
                const uint4 q01 = *(const uint4*)(pb + dX[k]);
                const uint4 q10 = *(const uint4*)(pb + dY[k]);
                const uint4 q11 = *(const uint4*)(pb + dX[k] + dY[k]);
                a0 += w00[k] * bf_lo(q00.x) + w01[k] * bf_lo(q01.x)
                    + w10[k] * bf_lo(q10.x) + w11[k] * bf_lo(q11.x);
                a1 += w00[k] * bf_hi(q00.x) + w01[k] * bf_hi(q01.x)
                    + w10[k] * bf_hi(q10.x) + w11[k] * bf_hi(q11.x);
                a2 += w00[k] * bf_lo(q00.y) + w01[k] * bf_lo(q01.y)
                    + w10[k] * bf_lo(q10.y) + w11[k] * bf_lo(q11.y);
                a3 += w00[k] * bf_hi(q00.y) + w01[k] * bf_hi(q01.y)
                    + w10[k] * bf_hi(q10.y) + w11[k] * bf_hi(q11.y);
                a4 += w00[k] * bf_lo(q00.z) + w01[k] * bf_lo(q01.z)
                    + w10[k] * bf_lo(q10.z) + w11[k] * bf_lo(q11.z);
                a5 += w00[k] * bf_hi(q00.z) + w01[k] * bf_hi(q01.z)
                    + w10[k] * bf_hi(q10.z) + w11[k] * bf_hi(q11.z);
                a6 += w00[k] * bf_lo(q00.w) + w01[k] * bf_lo(q01.w)
                    + w10[k] * bf_lo(q10.w) + w11[k] * bf_lo(q11.w);
                a7 += w00[k] * bf_hi(q00.w) + w01[k] * bf_hi(q01.w)
                    + w10[k] * bf_hi(q10.w) + w11[k] * bf_hi(q11.w);
            }
            __builtin_nontemporal_store(a0, &outp[(size_t)(j * 8 + 0) * NPTS]);
            __builtin_nontemporal_store(a1, &outp[(size_t)(j * 8 + 1) * NPTS]);
            __builtin_nontemporal_store(a2, &outp[(size_t)(j * 8 + 2) * NPTS]);
            __builtin_nontemporal_store(a3, &outp[(size_t)(j * 8 + 3) * NPTS]);
            __builtin_nontemporal_store(a4, &outp[(size_t)(j * 8 + 4) * NPTS]);
            __builtin_nontemporal_store(a5, &outp[(size_t)(j * 8 + 5) * NPTS]);
            __builtin_nontemporal_store(a6, &outp[(size_t)(j * 8 + 6) * NPTS]);
            __builtin_nontemporal_store(a7, &outp[(size_t)(j * 8 + 7) * NPTS]);
        }
    } else {
        const float* feat = (const float*)featv;
#pragma unroll 1
        for (int c = 0; c < JPT * 8; ++c) {
            float a = 0.0f;
#pragma unroll
            for (int k = 0; k < K_; ++k) {
                if (!val[k]) continue;
                const float* pb = feat + off[k] + (size_t)(cs * JPT * 8 + c) * P_;
                a += w00[k] * pb[0] + w01[k] * pb[dX[k]]
                   + w10[k] * pb[dY[k]] + w11[k] * pb[dX[k] + dY[k]];
            }
            __builtin_nontemporal_store(a, &outp[(size_t)c * NPTS]);
        }
    }
}

extern "C" void kernel_launch(void* const* d_in, const int* in_sizes, int n_in,
                              void* d_out, int out_size, void* d_ws, size_t ws_size,
                              hipStream_t stream) {
    const float* features   = (const float*)d_in[0];
    const float* intrinsics = (const float*)d_in[1];
    const float* extrinsics = (const float*)d_in[2];
    float* out = (float*)d_out;

    const size_t need = sizeof(uint4) * (size_t)BK_ * C8_ * P_;  // ~17 MB
    if (ws_size >= need) {
        uint4* featT = (uint4*)d_ws;
        shuffle_feat_bf16<<<dim3(P_ / 64, BK_), 256, 0, stream>>>(features, featT);
        bev_project<true><<<dim3(BEV, B_, CSPLIT), 256, 0, stream>>>(
            (const void*)featT, intrinsics, extrinsics, out);
    } else {
        bev_project<false><<<dim3(BEV, B_, CSPLIT), 256, 0, stream>>>(
            (const void*)features, intrinsics, extrinsics, out);
    }
}

// Round 8
// 59.166 us; speedup vs baseline: 1.4491x; 1.0480x over previous
//
#include <hip/hip_runtime.h>

#define B_   4
#define K_   6
#define BK_  (B_ * K_)
#define C_   128
#define C8_  (C_ / 8)         // 16 channel-blocks of 8
#define HF_  32
#define WF_  88
#define P_   (HF_ * WF_)      // 2816 pixels per (b,k) feature map
#define BEV  256
#define NPTS (BEV * BEV)      // 65536
#define CSPLIT 4              // channel slices (grid.z)
#define JPT  (C8_ / CSPLIT)   // 4 channel-blocks (of 8) per thread

__device__ __forceinline__ unsigned short f32_to_bf16_rne(float f) {
    union { float f; unsigned int u; } c; c.f = f;
    unsigned int u = c.u;
    u += 0x7fffu + ((u >> 16) & 1u);   // round to nearest even
    return (unsigned short)(u >> 16);
}
__device__ __forceinline__ float bf_lo(unsigned int w) {
    union { unsigned int u; float f; } c; c.u = w << 16; return c.f;
}
__device__ __forceinline__ float bf_hi(unsigned int w) {
    union { unsigned int u; float f; } c; c.u = w & 0xffff0000u; return c.f;
}

// ---------------------------------------------------------------------------
// Kernel 1: shuffle features [BK, C, P] (f32) -> [BK, C/8, P, 8] packed bf16.
// 16 B per (pixel, 8-channel block): one aligned uint4 gather = 8 channels.
// ---------------------------------------------------------------------------
__global__ __launch_bounds__(256) void shuffle_feat_bf16(
    const float* __restrict__ in, uint4* __restrict__ outT)
{
    __shared__ float lds[64][C_ + 1];
    const int bk  = blockIdx.y;
    const int p0  = blockIdx.x * 64;
    const int tid = threadIdx.x;

    const int pl = tid & 63;        // pixel within tile
    const int cq = tid >> 6;        // 0..3 channel sub-lane (read phase)
    const float* src = in + (size_t)bk * C_ * P_;
#pragma unroll
    for (int c0 = 0; c0 < C_; c0 += 4) {
        const int c = c0 + cq;
        lds[pl][c] = src[(size_t)c * P_ + p0 + pl];
    }
    __syncthreads();

    // write phase: pack 8 channels of one pixel into 16 B; lanes over pixels
    uint4* dst = outT + (size_t)bk * C8_ * P_;
    const int cbq = tid >> 6;       // 0..3 cb sub-lane
#pragma unroll
    for (int cb0 = 0; cb0 < C8_; cb0 += 4) {
        const int cb = cb0 + cbq;
        const float* row = &lds[pl][cb * 8];
        uint4 q;
        q.x = (unsigned int)f32_to_bf16_rne(row[0]) | ((unsigned int)f32_to_bf16_rne(row[1]) << 16);
        q.y = (unsigned int)f32_to_bf16_rne(row[2]) | ((unsigned int)f32_to_bf16_rne(row[3]) << 16);
        q.z = (unsigned int)f32_to_bf16_rne(row[4]) | ((unsigned int)f32_to_bf16_rne(row[5]) << 16);
        q.w = (unsigned int)f32_to_bf16_rne(row[6]) | ((unsigned int)f32_to_bf16_rne(row[7]) << 16);
        dst[(size_t)cb * P_ + p0 + pl] = q;
    }
}

// ---------------------------------------------------------------------------
// Kernel 2: per-BEV-point projection + bilinear sampling over 6 cameras.
// Grid: (256 16x16-tiles, B, CSPLIT); block 256 threads = one 16x16 BEV tile
// (wave = 16x4 patch) so camera validity is wave-uniform: exec-mask branches
// skip whole cameras per wave instead of running the union of lane sets.
// ---------------------------------------------------------------------------
template <bool TRANS>
__global__ __launch_bounds__(256) void bev_project(
    const void* __restrict__ featv,
    const float* __restrict__ intr,   // [B,K,3,3]
    const float* __restrict__ extr,   // [B,K,4,4]
    float* __restrict__ out)          // [B,C,BEV,BEV]
{
    const int tid = threadIdx.x;
    const int ix  = (blockIdx.x & 15) * 16 + (tid & 15);
    const int iy  = (blockIdx.x >> 4) * 16 + (tid >> 4);
    const int b   = blockIdx.y;
    const int cs  = blockIdx.z;

    const float STEP = 102.4f / 255.0f;
    const float gx = -51.2f + ix * STEP;
    const float gy = -51.2f + iy * STEP;

    int   off[K_], dX[K_], dY[K_];
    float w00[K_], w01[K_], w10[K_], w11[K_];
    bool  val[K_];
    float cnt = 0.0f;

#pragma unroll
    for (int k = 0; k < K_; ++k) {
        const float* E = extr + (size_t)(b * K_ + k) * 16;
        const float* I = intr + (size_t)(b * K_ + k) * 9;
        // world z = 0, w = 1
        const float c0 = E[0] * gx + E[1] * gy + E[3];
        const float c1 = E[4] * gx + E[5] * gy + E[7];
        const float c2 = E[8] * gx + E[9] * gy + E[11];
        const float uu = I[0] * c0 + I[1] * c1 + I[2] * c2;
        const float vv = I[3] * c0 + I[4] * c1 + I[5] * c2;
        const float ww = I[6] * c0 + I[7] * c1 + I[8] * c2;
        const float depth = fmaxf(ww, 1e-5f);
        const float u = uu / depth * 0.125f;   // sx = 88/704
        const float v = vv / depth * 0.125f;   // sy = 32/256
        const bool valid = (ww > 1e-3f) && (u >= 0.0f) && (u <= (float)(WF_ - 1))
                                        && (v >= 0.0f) && (v <= (float)(HF_ - 1));
        const float uc = fminf(fmaxf(u, 0.0f), (float)(WF_ - 1));
        const float vc = fminf(fmaxf(v, 0.0f), (float)(HF_ - 1));
        const float x0f = floorf(uc), y0f = floorf(vc);
        const int x0 = (int)x0f, y0 = (int)y0f;
        const int x1 = min(x0 + 1, WF_ - 1), y1 = min(y0 + 1, HF_ - 1);
        const float wx = uc - x0f, wy = vc - y0f;

        val[k] = valid;
        cnt += valid ? 1.0f : 0.0f;
        w00[k] = (1.0f - wx) * (1.0f - wy);
        w01[k] = wx * (1.0f - wy);
        w10[k] = (1.0f - wx) * wy;
        w11[k] = wx * wy;

        const int pix = y0 * WF_ + x0;
        if (TRANS) {
            off[k] = ((b * K_ + k) * C8_ * P_ + pix) * 16;  // byte offset
            dX[k]  = (x1 - x0) * 16;                        // bytes
            dY[k]  = (y1 - y0) * (WF_ * 16);                // bytes
        } else {
            off[k] = (b * K_ + k) * (C_ * P_) + pix;
            dX[k]  = (x1 - x0);
            dY[k]  = (y1 - y0) * WF_;
        }
    }

    const float inv = 1.0f / fmaxf(cnt, 1.0f);
#pragma unroll
    for (int k = 0; k < K_; ++k) {       // fold 1/count into the weights
        w00[k] *= inv; w01[k] *= inv; w10[k] *= inv; w11[k] *= inv;
    }

    float* outp = out + (size_t)b * C_ * NPTS + (size_t)(cs * JPT * 8) * NPTS
                      + (size_t)iy * BEV + ix;

    if (TRANS) {
        const char* bp[K_];
#pragma unroll
        for (int k = 0; k < K_; ++k)
            bp[k] = (const char*)featv + off[k] + (size_t)(cs * JPT) * (P_ * 16);

#pragma unroll 1
        for (int j = 0; j < JPT; ++j) {
            float a0 = 0.0f, a1 = 0.0f, a2 = 0.0f, a3 = 0.0f;
            float a4 = 0.0f, a5 = 0.0f, a6 = 0.0f, a7 = 0.0f;
#pragma unroll
            for (int k = 0; k < K_; ++k) {
                if (!val[k]) continue;
                const char* pb = bp[k] + j * (P_ * 16);
                const uint4 q00 = *(const uint4*)(pb);
                const uint4 q01 = *(const uint4*)(pb + dX[k]);
                const uint4 q10 = *(const uint4*)(pb + dY[k]);
                const uint4 q11 = *(const uint4*)(pb + dX[k] + dY[k]);
                a0 += w00[k] * bf_lo(q00.x) + w01[k] * bf_lo(q01.x)
                    + w10[k] * bf_lo(q10.x) + w11[k] * bf_lo(q11.x);
                a1 += w00[k] * bf_hi(q00.x) + w01[k] * bf_hi(q01.x)
                    + w10[k] * bf_hi(q10.x) + w11[k] * bf_hi(q11.x);
                a2 += w00[k] * bf_lo(q00.y) + w01[k] * bf_lo(q01.y)
                    + w10[k] * bf_lo(q10.y) + w11[k] * bf_lo(q11.y);
                a3 += w00[k] * bf_hi(q00.y) + w01[k] * bf_hi(q01.y)
                    + w10[k] * bf_hi(q10.y) + w11[k] * bf_hi(q11.y);
                a4 += w00[k] * bf_lo(q00.z) + w01[k] * bf_lo(q01.z)
                    + w10[k] * bf_lo(q10.z) + w11[k] * bf_lo(q11.z);
                a5 += w00[k] * bf_hi(q00.z) + w01[k] * bf_hi(q01.z)
                    + w10[k] * bf_hi(q10.z) + w11[k] * bf_hi(q11.z);
                a6 += w00[k] * bf_lo(q00.w) + w01[k] * bf_lo(q01.w)
                    + w10[k] * bf_lo(q10.w) + w11[k] * bf_lo(q11.w);
                a7 += w00[k] * bf_hi(q00.w) + w01[k] * bf_hi(q01.w)
                    + w10[k] * bf_hi(q10.w) + w11[k] * bf_hi(q11.w);
            }
            __builtin_nontemporal_store(a0, &outp[(size_t)(j * 8 + 0) * NPTS]);
            __builtin_nontemporal_store(a1, &outp[(size_t)(j * 8 + 1) * NPTS]);
            __builtin_nontemporal_store(a2, &outp[(size_t)(j * 8 + 2) * NPTS]);
            __builtin_nontemporal_store(a3, &outp[(size_t)(j * 8 + 3) * NPTS]);
            __builtin_nontemporal_store(a4, &outp[(size_t)(j * 8 + 4) * NPTS]);
            __builtin_nontemporal_store(a5, &outp[(size_t)(j * 8 + 5) * NPTS]);
            __builtin_nontemporal_store(a6, &outp[(size_t)(j * 8 + 6) * NPTS]);
            __builtin_nontemporal_store(a7, &outp[(size_t)(j * 8 + 7) * NPTS]);
        }
    } else {
        const float* feat = (const float*)featv;
#pragma unroll 1
        for (int c = 0; c < JPT * 8; ++c) {
            float a = 0.0f;
#pragma unroll
            for (int k = 0; k < K_; ++k) {
                if (!val[k]) continue;
                const float* pb = feat + off[k] + (size_t)(cs * JPT * 8 + c) * P_;
                a += w00[k] * pb[0] + w01[k] * pb[dX[k]]
                   + w10[k] * pb[dY[k]] + w11[k] * pb[dX[k] + dY[k]];
            }
            __builtin_nontemporal_store(a, &outp[(size_t)c * NPTS]);
        }
    }
}

extern "C" void kernel_launch(void* const* d_in, const int* in_sizes, int n_in,
                              void* d_out, int out_size, void* d_ws, size_t ws_size,
                              hipStream_t stream) {
    const float* features   = (const float*)d_in[0];
    const float* intrinsics = (const float*)d_in[1];
    const float* extrinsics = (const float*)d_in[2];
    float* out = (float*)d_out;

    const size_t need = sizeof(uint4) * (size_t)BK_ * C8_ * P_;  // ~17 MB
    if (ws_size >= need) {
        uint4* featT = (uint4*)d_ws;
        shuffle_feat_bf16<<<dim3(P_ / 64, BK_), 256, 0, stream>>>(features, featT);
        bev_project<true><<<dim3(256, B_, CSPLIT), 256, 0, stream>>>(
            (const void*)featT, intrinsics, extrinsics, out);
    } else {
        bev_project<false><<<dim3(256, B_, CSPLIT), 256, 0, stream>>>(
            (const void*)features, intrinsics, extrinsics, out);
    }
}

// Round 9
// 57.840 us; speedup vs baseline: 1.4823x; 1.0229x over previous
//
#include <hip/hip_runtime.h>

#define B_   4
#define K_   6
#define BK_  (B_ * K_)
#define C_   128
#define C8_  (C_ / 8)         // 16 channel-blocks of 8
#define HF_  32
#define WF_  88
#define P_   (HF_ * WF_)      // 2816 pixels per (b,k) feature map
#define BEV  256
#define NPTS (BEV * BEV)      // 65536
#define CSPLIT 2              // channel slices (grid.z)
#define JPT  (C8_ / CSPLIT)   // 8 channel-blocks (of 8) per thread

__device__ __forceinline__ unsigned short f32_to_bf16_rne(float f) {
    union { float f; unsigned int u; } c; c.f = f;
    unsigned int u = c.u;
    u += 0x7fffu + ((u >> 16) & 1u);   // round to nearest even
    return (unsigned short)(u >> 16);
}
__device__ __forceinline__ float bf_lo(unsigned int w) {
    union { unsigned int u; float f; } c; c.u = w << 16; return c.f;
}
__device__ __forceinline__ float bf_hi(unsigned int w) {
    union { unsigned int u; float f; } c; c.u = w & 0xffff0000u; return c.f;
}

// ---------------------------------------------------------------------------
// Kernel 1: shuffle features [BK, C, P] (f32) -> [BK, C/8, P, 8] packed bf16.
// 16 B per (pixel, 8-channel block): one aligned uint4 gather = 8 channels.
// ---------------------------------------------------------------------------
__global__ __launch_bounds__(256) void shuffle_feat_bf16(
    const float* __restrict__ in, uint4* __restrict__ outT)
{
    __shared__ float lds[64][C_ + 1];
    const int bk  = blockIdx.y;
    const int p0  = blockIdx.x * 64;
    const int tid = threadIdx.x;

    const int pl = tid & 63;        // pixel within tile
    const int cq = tid >> 6;        // 0..3 channel sub-lane (read phase)
    const float* src = in + (size_t)bk * C_ * P_;
#pragma unroll
    for (int c0 = 0; c0 < C_; c0 += 4) {
        const int c = c0 + cq;
        lds[pl][c] = src[(size_t)c * P_ + p0 + pl];
    }
    __syncthreads();

    // write phase: pack 8 channels of one pixel into 16 B; lanes over pixels
    uint4* dst = outT + (size_t)bk * C8_ * P_;
    const int cbq = tid >> 6;       // 0..3 cb sub-lane
#pragma unroll
    for (int cb0 = 0; cb0 < C8_; cb0 += 4) {
        const int cb = cb0 + cbq;
        const float* row = &lds[pl][cb * 8];
        uint4 q;
        q.x = (unsigned int)f32_to_bf16_rne(row[0]) | ((unsigned int)f32_to_bf16_rne(row[1]) << 16);
        q.y = (unsigned int)f32_to_bf16_rne(row[2]) | ((unsigned int)f32_to_bf16_rne(row[3]) << 16);
        q.z = (unsigned int)f32_to_bf16_rne(row[4]) | ((unsigned int)f32_to_bf16_rne(row[5]) << 16);
        q.w = (unsigned int)f32_to_bf16_rne(row[6]) | ((unsigned int)f32_to_bf16_rne(row[7]) << 16);
        dst[(size_t)cb * P_ + p0 + pl] = q;
    }
}

// ---------------------------------------------------------------------------
// Kernel 2: per-BEV-point projection + bilinear sampling over 6 cameras.
// Grid: (256 32x8-tiles, B, CSPLIT); block 256 threads = one 32x8 BEV tile.
// Wave = 32x2 patch: camera validity still near-wave-uniform (gather
// locality), while each 32-lane row stores a FULL 128-B line (nontemporal
// partial-line drain was R8's store regression). CSPLIT=2: geometry runs
// 2x per point instead of 4x; 2048 blocks = 8/CU keeps residency maxed.
// ---------------------------------------------------------------------------
template <bool TRANS>
__global__ __launch_bounds__(256) void bev_project(
    const void* __restrict__ featv,
    const float* __restrict__ intr,   // [B,K,3,3]
    const float* __restrict__ extr,   // [B,K,4,4]
    float* __restrict__ out)          // [B,C,BEV,BEV]
{
    const int tid = threadIdx.x;
    const int ix  = (blockIdx.x & 7) * 32 + (tid & 31);
    const int iy  = (blockIdx.x >> 3) * 8 + (tid >> 5);
    const int b   = blockIdx.y;
    const int cs  = blockIdx.z;

    const float STEP = 102.4f / 255.0f;
    const float gx = -51.2f + ix * STEP;
    const float gy = -51.2f + iy * STEP;

    int   off[K_], dX[K_], dY[K_];
    float w00[K_], w01[K_], w10[K_], w11[K_];
    bool  val[K_];
    float cnt = 0.0f;

#pragma unroll
    for (int k = 0; k < K_; ++k) {
        const float* E = extr + (size_t)(b * K_ + k) * 16;
        const float* I = intr + (size_t)(b * K_ + k) * 9;
        // world z = 0, w = 1
        const float c0 = E[0] * gx + E[1] * gy + E[3];
        const float c1 = E[4] * gx + E[5] * gy + E[7];
        const float c2 = E[8] * gx + E[9] * gy + E[11];
        const float uu = I[0] * c0 + I[1] * c1 + I[2] * c2;
        const float vv = I[3] * c0 + I[4] * c1 + I[5] * c2;
        const float ww = I[6] * c0 + I[7] * c1 + I[8] * c2;
        const float depth = fmaxf(ww, 1e-5f);
        const float u = uu / depth * 0.125f;   // sx = 88/704
        const float v = vv / depth * 0.125f;   // sy = 32/256
        const bool valid = (ww > 1e-3f) && (u >= 0.0f) && (u <= (float)(WF_ - 1))
                                        && (v >= 0.0f) && (v <= (float)(HF_ - 1));
        const float uc = fminf(fmaxf(u, 0.0f), (float)(WF_ - 1));
        const float vc = fminf(fmaxf(v, 0.0f), (float)(HF_ - 1));
        const float x0f = floorf(uc), y0f = floorf(vc);
        const int x0 = (int)x0f, y0 = (int)y0f;
        const int x1 = min(x0 + 1, WF_ - 1), y1 = min(y0 + 1, HF_ - 1);
        const float wx = uc - x0f, wy = vc - y0f;

        val[k] = valid;
        cnt += valid ? 1.0f : 0.0f;
        w00[k] = (1.0f - wx) * (1.0f - wy);
        w01[k] = wx * (1.0f - wy);
        w10[k] = (1.0f - wx) * wy;
        w11[k] = wx * wy;

        const int pix = y0 * WF_ + x0;
        if (TRANS) {
            off[k] = ((b * K_ + k) * C8_ * P_ + pix) * 16;  // byte offset
            dX[k]  = (x1 - x0) * 16;                        // bytes
            dY[k]  = (y1 - y0) * (WF_ * 16);                // bytes
        } else {
            off[k] = (b * K_ + k) * (C_ * P_) + pix;
            dX[k]  = (x1 - x0);
            dY[k]  = (y1 - y0) * WF_;
        }
    }

    const float inv = 1.0f / fmaxf(cnt, 1.0f);
#pragma unroll
    for (int k = 0; k < K_; ++k) {       // fold 1/count into the weights
        w00[k] *= inv; w01[k] *= inv; w10[k] *= inv; w11[k] *= inv;
    }

    float* outp = out + (size_t)b * C_ * NPTS + (size_t)(cs * JPT * 8) * NPTS
                      + (size_t)iy * BEV + ix;

    if (TRANS) {
        const char* bp[K_];
#pragma unroll
        for (int k = 0; k < K_; ++k)
            bp[k] = (const char*)featv + off[k] + (size_t)(cs * JPT) * (P_ * 16);

#pragma unroll 1
        for (int j = 0; j < JPT; ++j) {
            float a0 = 0.0f, a1 = 0.0f, a2 = 0.0f, a3 = 0.0f;
            float a4 = 0.0f, a5 = 0.0f, a6 = 0.0f, a7 = 0.0f;
#pragma unroll
            for (int k = 0; k < K_; ++k) {
                if (!val[k]) continue;
                const char* pb = bp[k] + j * (P_ * 16);
                const uint4 q00 = *(const uint4*)(pb);
                const uint4 q01 = *(const uint4*)(pb + dX[k]);
                const uint4 q10 = *(const uint4*)(pb + dY[k]);
                const uint4 q11 = *(const uint4*)(pb + dX[k] + dY[k]);
                a0 += w00[k] * bf_lo(q00.x) + w01[k] * bf_lo(q01.x)
                    + w10[k] * bf_lo(q10.x) + w11[k] * bf_lo(q11.x);
                a1 += w00[k] * bf_hi(q00.x) + w01[k] * bf_hi(q01.x)
                    + w10[k] * bf_hi(q10.x) + w11[k] * bf_hi(q11.x);
                a2 += w00[k] * bf_lo(q00.y) + w01[k] * bf_lo(q01.y)
                    + w10[k] * bf_lo(q10.y) + w11[k] * bf_lo(q11.y);
                a3 += w00[k] * bf_hi(q00.y) + w01[k] * bf_hi(q01.y)
                    + w10[k] * bf_hi(q10.y) + w11[k] * bf_hi(q11.y);
                a4 += w00[k] * bf_lo(q00.z) + w01[k] * bf_lo(q01.z)
                    + w10[k] * bf_lo(q10.z) + w11[k] * bf_lo(q11.z);
                a5 += w00[k] * bf_hi(q00.z) + w01[k] * bf_hi(q01.z)
                    + w10[k] * bf_hi(q10.z) + w11[k] * bf_hi(q11.z);
                a6 += w00[k] * bf_lo(q00.w) + w01[k] * bf_lo(q01.w)
                    + w10[k] * bf_lo(q10.w) + w11[k] * bf_lo(q11.w);
                a7 += w00[k] * bf_hi(q00.w) + w01[k] * bf_hi(q01.w)
                    + w10[k] * bf_hi(q10.w) + w11[k] * bf_hi(q11.w);
            }
            __builtin_nontemporal_store(a0, &outp[(size_t)(j * 8 + 0) * NPTS]);
            __builtin_nontemporal_store(a1, &outp[(size_t)(j * 8 + 1) * NPTS]);
            __builtin_nontemporal_store(a2, &outp[(size_t)(j * 8 + 2) * NPTS]);
            __builtin_nontemporal_store(a3, &outp[(size_t)(j * 8 + 3) * NPTS]);
            __builtin_nontemporal_store(a4, &outp[(size_t)(j * 8 + 4) * NPTS]);
            __builtin_nontemporal_store(a5, &outp[(size_t)(j * 8 + 5) * NPTS]);
            __builtin_nontemporal_store(a6, &outp[(size_t)(j * 8 + 6) * NPTS]);
            __builtin_nontemporal_store(a7, &outp[(size_t)(j * 8 + 7) * NPTS]);
        }
    } else {
        const float* feat = (const float*)featv;
#pragma unroll 1
        for (int c = 0; c < JPT * 8; ++c) {
            float a = 0.0f;
#pragma unroll
            for (int k = 0; k < K_; ++k) {
                if (!val[k]) continue;
                const float* pb = feat + off[k] + (size_t)(cs * JPT * 8 + c) * P_;
                a += w00[k] * pb[0] + w01[k] * pb[dX[k]]
                   + w10[k] * pb[dY[k]] + w11[k] * pb[dX[k] + dY[k]];
            }
            __builtin_nontemporal_store(a, &outp[(size_t)c * NPTS]);
        }
    }
}

extern "C" void kernel_launch(void* const* d_in, const int* in_sizes, int n_in,
                              void* d_out, int out_size, void* d_ws, size_t ws_size,
                              hipStream_t stream) {
    const float* features   = (const float*)d_in[0];
    const float* intrinsics = (const float*)d_in[1];
    const float* extrinsics = (const float*)d_in[2];
    float* out = (float*)d_out;

    const size_t need = sizeof(uint4) * (size_t)BK_ * C8_ * P_;  // ~17 MB
    if (ws_size >= need) {
        uint4* featT = (uint4*)d_ws;
        shuffle_feat_bf16<<<dim3(P_ / 64, BK_), 256, 0, stream>>>(features, featT);
        bev_project<true><<<dim3(256, B_, CSPLIT), 256, 0, stream>>>(
            (const void*)featT, intrinsics, extrinsics, out);
    } else {
        bev_project<false><<<dim3(256, B_, CSPLIT), 256, 0, stream>>>(
            (const void*)features, intrinsics, extrinsics, out);
    }
}